// Round 8
// baseline (415.491 us; speedup 1.0000x reference)
//
#include <hip/hip_runtime.h>
#include <stdint.h>

typedef unsigned short u16;
typedef __attribute__((ext_vector_type(8))) short bf16x8;
typedef __attribute__((ext_vector_type(4))) float f32x4;

#define T_TOK 4096
#define D_DIM 1024
#define F_DIM 2048
#define NEXP 8
#define BM 128
#define BK 64
#define NDESC1 64     // 256-row tiles for gemm1
#define NDESC2 112    // 128-row tiles for gemm2

struct Desc { int row_start; int nrows; int e; int pad; };

__device__ __forceinline__ u16 f2bf(float x) {
  union { float f; unsigned u; } v; v.f = x;
  unsigned r = v.u + 0x7FFFu + ((v.u >> 16) & 1u);
  return (u16)(r >> 16);
}

#define GLD16(g, l) __builtin_amdgcn_global_load_lds( \
    (const __attribute__((address_space(1))) unsigned int*)(const void*)(g), \
    (__attribute__((address_space(3))) unsigned int*)(void*)(l), 16, 0, 0)

#define SBARF() do { asm volatile("" ::: "memory"); \
                     __builtin_amdgcn_s_barrier(); \
                     asm volatile("" ::: "memory"); } while (0)
#define WAITV(n) asm volatile("s_waitcnt vmcnt(" #n ")" ::: "memory")

// ------ convert + transpose ALL weights; grid (16,32,27); zeroes meta once ------
__global__ void k_tconv_all(const float* __restrict__ Wg_s, const float* __restrict__ Wu_s,
                            const float* __restrict__ Wd_s, const float* __restrict__ Wg,
                            const float* __restrict__ Wu, const float* __restrict__ Wd,
                            u16* __restrict__ WgTs, u16* __restrict__ WuTs,
                            u16* __restrict__ WdTs, u16* __restrict__ WgT,
                            u16* __restrict__ WuT, u16* __restrict__ WdT,
                            int* __restrict__ meta) {
  if (blockIdx.x == 0 && blockIdx.y == 0 && blockIdx.z == 0 && threadIdx.x < 32)
    meta[threadIdx.x] = 0;
  const int z = blockIdx.z;
  const float* src; u16* dst; int R, C;
  const size_t sz = (size_t)D_DIM * F_DIM;
  if (z < 8)       { src = Wg + sz * z;        dst = WgT + sz * z;        R = D_DIM; C = F_DIM; }
  else if (z < 16) { src = Wu + sz * (z - 8);  dst = WuT + sz * (z - 8);  R = D_DIM; C = F_DIM; }
  else if (z < 24) { src = Wd + sz * (z - 16); dst = WdT + sz * (z - 16); R = F_DIM; C = D_DIM; }
  else if (z == 24){ src = Wg_s; dst = WgTs; R = D_DIM; C = F_DIM; }
  else if (z == 25){ src = Wu_s; dst = WuTs; R = D_DIM; C = F_DIM; }
  else             { src = Wd_s; dst = WdTs; R = F_DIM; C = D_DIM; }
  const bool tall = (R > C);
  const int rb = (tall ? blockIdx.y : blockIdx.x) * 64;
  const int cb = (tall ? blockIdx.x : blockIdx.y) * 64;
  __shared__ u16 tile[64][72];
  const int tid = threadIdx.x;
  const int lr = tid >> 4, lc = (tid & 15) * 4;
  #pragma unroll
  for (int p = 0; p < 4; p++) {
    int r = p * 16 + lr;
    float4 v = *(const float4*)(src + (size_t)(rb + r) * C + cb + lc);
    tile[r][lc + 0] = f2bf(v.x); tile[r][lc + 1] = f2bf(v.y);
    tile[r][lc + 2] = f2bf(v.z); tile[r][lc + 3] = f2bf(v.w);
  }
  __syncthreads();
  #pragma unroll
  for (int it = 0; it < 2; it++) {
    int chunk = it * 256 + tid;
    int c = chunk >> 3, r0 = (chunk & 7) * 8;
    u16 o[8];
    #pragma unroll
    for (int i = 0; i < 8; i++) o[i] = tile[r0 + i][c];
    *(uint4*)(dst + (size_t)(cb + c) * R + rb + r0) = *(const uint4*)o;
  }
}

// ------- router (fp32 logits, softmax, top-2, re-softmax) + X->bf16 convert -------
__global__ void k_router(const float* __restrict__ X, const float* __restrict__ Wr,
                         u16* __restrict__ Xb, int* __restrict__ tk_idx,
                         float* __restrict__ tk_w, int* __restrict__ counts) {
  const int w = threadIdx.x >> 6, lane = threadIdx.x & 63;
  const int t = blockIdx.x * 4 + w;
  float acc[8] = {0.f, 0.f, 0.f, 0.f, 0.f, 0.f, 0.f, 0.f};
  const float* xr = X + (size_t)t * D_DIM;
  u16* xb = Xb + (size_t)t * D_DIM;
  #pragma unroll
  for (int it = 0; it < 4; it++) {
    const int i0 = it * 256 + lane * 4;
    float4 xv = *(const float4*)(xr + i0);
    union { u16 a[4]; uint2 v; } ob;
    ob.a[0] = f2bf(xv.x); ob.a[1] = f2bf(xv.y); ob.a[2] = f2bf(xv.z); ob.a[3] = f2bf(xv.w);
    *(uint2*)(xb + i0) = ob.v;
    float xs[4] = {xv.x, xv.y, xv.z, xv.w};
    #pragma unroll
    for (int j = 0; j < 4; j++) {
      const float4* wrp = (const float4*)(Wr + (size_t)(i0 + j) * 8);
      float4 w0 = wrp[0], w1 = wrp[1];
      float x = xs[j];
      acc[0] += x * w0.x; acc[1] += x * w0.y; acc[2] += x * w0.z; acc[3] += x * w0.w;
      acc[4] += x * w1.x; acc[5] += x * w1.y; acc[6] += x * w1.z; acc[7] += x * w1.w;
    }
  }
  #pragma unroll
  for (int m = 32; m; m >>= 1) {
    #pragma unroll
    for (int e = 0; e < 8; e++) acc[e] += __shfl_xor(acc[e], m);
  }
  float mx = acc[0];
  #pragma unroll
  for (int e = 1; e < 8; e++) mx = fmaxf(mx, acc[e]);
  float p[8], Z = 0.f;
  #pragma unroll
  for (int e = 0; e < 8; e++) { p[e] = expf(acc[e] - mx); Z += p[e]; }
  float inv = 1.f / Z;
  #pragma unroll
  for (int e = 0; e < 8; e++) p[e] *= inv;
  int e1 = 0; float p1 = p[0];
  #pragma unroll
  for (int e = 1; e < 8; e++) if (p[e] > p1) { p1 = p[e]; e1 = e; }
  int e2 = -1; float p2 = -1.f;
  #pragma unroll
  for (int e = 0; e < 8; e++) if (e != e1 && p[e] > p2) { p2 = p[e]; e2 = e; }
  float bb = expf(p2 - p1);
  float w1v = 1.f / (1.f + bb), w2v = 1.f - w1v;
  if (lane == 0) {
    tk_idx[t * 2] = e1; tk_idx[t * 2 + 1] = e2;
    tk_w[t * 2] = w1v;  tk_w[t * 2 + 1] = w2v;
    atomicAdd(&counts[e1], 1); atomicAdd(&counts[e2], 1);
  }
}

// ------- scan: 256-row descs (gemm1) + 128-row descs (gemm2), parallel -------
__global__ void k_scan(const int* __restrict__ counts, int* __restrict__ offsets,
                       int* __restrict__ cursors, Desc* __restrict__ d1,
                       Desc* __restrict__ d2) {
  const int lane = threadIdx.x;
  int cnt[8], off[9], tA[9], tB[9];
  off[0] = 0; tA[0] = 0; tB[0] = 0;
  #pragma unroll
  for (int e = 0; e < 8; e++) {
    cnt[e] = counts[e];
    off[e + 1] = off[e] + cnt[e];
    tA[e + 1] = tA[e] + ((cnt[e] + 255) >> 8);
    tB[e + 1] = tB[e] + ((cnt[e] + 127) >> 7);
  }
  if (lane < 8) { offsets[lane] = off[lane]; cursors[lane] = 0; }
  const int trA = tA[8], trB = tB[8];
  if (lane < NDESC1) {
    int i = lane;
    Desc dd; dd.nrows = 0; dd.row_start = 0; dd.e = 0; dd.pad = 0;
    if (i < trA) {
      int e = 0;
      #pragma unroll
      for (int q = 0; q < 7; q++) if (i >= tA[q + 1]) e = q + 1;
      int s = (i - tA[e]) << 8;
      dd.row_start = off[e] + s;
      int rem = cnt[e] - s;
      dd.nrows = rem < 256 ? rem : 256;
      dd.e = e;
    } else if (i < trA + T_TOK / 256) {
      int j = i - trA;
      dd.row_start = 2 * T_TOK + j * 256; dd.nrows = 256; dd.e = NEXP;
    }
    d1[i] = dd;
  }
  for (int i = lane; i < NDESC2; i += 64) {
    Desc dd; dd.nrows = 0; dd.row_start = 0; dd.e = 0; dd.pad = 0;
    if (i < trB) {
      int e = 0;
      #pragma unroll
      for (int q = 0; q < 7; q++) if (i >= tB[q + 1]) e = q + 1;
      int s = (i - tB[e]) << 7;
      dd.row_start = off[e] + s;
      int rem = cnt[e] - s;
      dd.nrows = rem < 128 ? rem : 128;
      dd.e = e;
    } else if (i < trB + T_TOK / 128) {
      int j = i - trB;
      dd.row_start = 2 * T_TOK + j * 128; dd.nrows = 128; dd.e = NEXP;
    }
    d2[i] = dd;
  }
}

// ---------------- scatter ----------------
__global__ void k_scatter(const int* __restrict__ tk_idx, const int* __restrict__ offsets,
                          int* __restrict__ cursors, int* __restrict__ tok,
                          int* __restrict__ pos) {
  int t = blockIdx.x * 256 + threadIdx.x;
  if (t >= T_TOK) return;
  #pragma unroll
  for (int k = 0; k < 2; k++) {
    int e = tk_idx[t * 2 + k];
    int pp = atomicAdd(&cursors[e], 1);
    int a = offsets[e] + pp;
    tok[a] = t;
    pos[t * 2 + k] = a;
  }
  tok[2 * T_TOK + t] = t;
}

// ======== GEMM1 fused: m201-style 4-phase/K-tile, 2-buf, counted vmcnt ========
// BM=256, BN=128(g)+128(u), BK=64. 512 thr = 8 waves (2M x 4N); per-wave output
// 128 rows x 32 g-cols + 128 x 32 u-cols (acc 32 f32x4 = 128 VGPR).
// LDS 128KB = 2 bufs x { A 32K (rows 0-255) | Bg 16K | Bu 16K }.
// Per K-tile, 4 phases; phase = {ds_read subtile; stage 2 gld_lds of tile t+1;
// counted vmcnt; s_barrier; setprio(1) 16 MFMA setprio(0); s_barrier}.
// Stage order = consume order 3-4 phases later: ph1 stages hA0(rows 0-63,128-191),
// ph2 hBg, ph3 hBu, ph4 hA1. Waits: vmcnt(4) at ph4/ph1/ph2 (tail 4/2/0). Never
// drain-0 in steady state (T4).
__global__ __launch_bounds__(512) void k_gemm1(
    const u16* __restrict__ Xb, const u16* __restrict__ WgT, const u16* __restrict__ WuT,
    const u16* __restrict__ WgTs, const u16* __restrict__ WuTs,
    const int* __restrict__ tok, const Desc* __restrict__ descs, u16* __restrict__ h) {
  __shared__ u16 lds[65536];                 // 131072 B
  const Desc d = descs[blockIdx.y];
  if (d.nrows <= 0) return;
  const int n0 = (int)blockIdx.x * 128;
  const u16* BTg = (d.e == NEXP) ? WgTs : (WgT + (size_t)d.e * F_DIM * D_DIM);
  const u16* BTu = (d.e == NEXP) ? WuTs : (WuT + (size_t)d.e * F_DIM * D_DIM);
  const int tid = threadIdx.x;
  const int w = tid >> 6, lane = tid & 63;
  const int wr = w >> 2, wc = w & 3;
  char* ldsc = (char*)lds;

  // staging sources (inverse-swizzled col; linear gld_lds dest; swizzled read)
  const int srow = tid >> 3;                 // 0..63
  const int scol = ((tid & 7) ^ (srow & 7)) * 8;
  const u16 *gA0 = Xb + (size_t)tok[d.row_start +   0 + srow] * D_DIM + scol;
  const u16 *gA1 = Xb + (size_t)tok[d.row_start +  64 + srow] * D_DIM + scol;
  const u16 *gA2 = Xb + (size_t)tok[d.row_start + 128 + srow] * D_DIM + scol;
  const u16 *gA3 = Xb + (size_t)tok[d.row_start + 192 + srow] * D_DIM + scol;
  const u16 *gG0 = BTg + (size_t)(n0 +  0 + srow) * D_DIM + scol;
  const u16 *gG1 = BTg + (size_t)(n0 + 64 + srow) * D_DIM + scol;
  const u16 *gU0 = BTu + (size_t)(n0 +  0 + srow) * D_DIM + scol;
  const u16 *gU1 = BTu + (size_t)(n0 + 64 + srow) * D_DIM + scol;
  const int sdst = tid * 16;

  // swizzled ds_read bases (within one 64KB buffer)
  const int slot0 = (((lane >> 4) ^ (lane & 7)) << 4);
  const int aoff = (wr * 128 + (lane & 15)) * 128 + slot0;   // + m*2048 (+8192 hi) ^ ks*64
  const int goff = 32768 + (wc * 32 + (lane & 15)) * 128 + slot0;
  const int uoff = goff + 16384;

  f32x4 ag[8][2], au[8][2];
  #pragma unroll
  for (int m = 0; m < 8; m++)
    #pragma unroll
    for (int n = 0; n < 2; n++) { ag[m][n] = (f32x4)0.f; au[m][n] = (f32x4)0.f; }

  // prologue: stage tile 0 into buf0 in consume order (A02, Bg, Bu, A13)
  GLD16(gA0, ldsc +     0 + sdst); gA0 += BK;
  GLD16(gA2, ldsc + 16384 + sdst); gA2 += BK;
  GLD16(gG0, ldsc + 32768 + sdst); gG0 += BK;
  GLD16(gG1, ldsc + 40960 + sdst); gG1 += BK;
  GLD16(gU0, ldsc + 49152 + sdst); gU0 += BK;
  GLD16(gU1, ldsc + 57344 + sdst); gU1 += BK;
  GLD16(gA1, ldsc +  8192 + sdst); gA1 += BK;
  GLD16(gA3, ldsc + 24576 + sdst); gA3 += BK;
  WAITV(4);
  SBARF();

  #pragma unroll 1
  for (int t = 0; t < 16; ++t) {
    char* cbp = ldsc + ((t & 1) << 16);
    char* sbp = ldsc + (((t & 1) ^ 1) << 16);
    const bool more = (t < 15);
    bf16x8 a[4][2], bgv[2][2], buv[2][2];
    // ---- ph1: read A-lo(8) + Bg(4); stage hA0(t+1); vmcnt; bar; MFMA g/m-lo; bar
    #pragma unroll
    for (int m = 0; m < 4; m++)
      #pragma unroll
      for (int ks = 0; ks < 2; ks++)
        a[m][ks] = *(const bf16x8*)(cbp + ((aoff + m * 2048) ^ (ks << 6)));
    #pragma unroll
    for (int n = 0; n < 2; n++)
      #pragma unroll
      for (int ks = 0; ks < 2; ks++)
        bgv[n][ks] = *(const bf16x8*)(cbp + ((goff + n * 2048) ^ (ks << 6)));
    if (more) { GLD16(gA0, sbp + 0 + sdst); gA0 += BK;
                GLD16(gA2, sbp + 16384 + sdst); gA2 += BK;
                WAITV(4); } else { WAITV(2); }
    SBARF();
    __builtin_amdgcn_s_setprio(1);
    #pragma unroll
    for (int m = 0; m < 4; m++)
      #pragma unroll
      for (int n = 0; n < 2; n++)
        #pragma unroll
        for (int ks = 0; ks < 2; ks++)
          ag[m][n] = __builtin_amdgcn_mfma_f32_16x16x32_bf16(a[m][ks], bgv[n][ks], ag[m][n], 0, 0, 0);
    __builtin_amdgcn_s_setprio(0);
    SBARF();
    // ---- ph2: read Bu(4); stage hBg(t+1); vmcnt; bar; MFMA u/m-lo; bar
    #pragma unroll
    for (int n = 0; n < 2; n++)
      #pragma unroll
      for (int ks = 0; ks < 2; ks++)
        buv[n][ks] = *(const bf16x8*)(cbp + ((uoff + n * 2048) ^ (ks << 6)));
    if (more) { GLD16(gG0, sbp + 32768 + sdst); gG0 += BK;
                GLD16(gG1, sbp + 40960 + sdst); gG1 += BK;
                WAITV(4); } else { WAITV(0); }
    SBARF();
    __builtin_amdgcn_s_setprio(1);
    #pragma unroll
    for (int m = 0; m < 4; m++)
      #pragma unroll
      for (int n = 0; n < 2; n++)
        #pragma unroll
        for (int ks = 0; ks < 2; ks++)
          au[m][n] = __builtin_amdgcn_mfma_f32_16x16x32_bf16(a[m][ks], buv[n][ks], au[m][n], 0, 0, 0);
    __builtin_amdgcn_s_setprio(0);
    SBARF();
    // ---- ph3: read A-hi(8); stage hBu(t+1); bar; MFMA g/m-hi; bar
    #pragma unroll
    for (int m = 0; m < 4; m++)
      #pragma unroll
      for (int ks = 0; ks < 2; ks++)
        a[m][ks] = *(const bf16x8*)(cbp + ((aoff + 8192 + m * 2048) ^ (ks << 6)));
    if (more) { GLD16(gU0, sbp + 49152 + sdst); gU0 += BK;
                GLD16(gU1, sbp + 57344 + sdst); gU1 += BK; }
    SBARF();
    __builtin_amdgcn_s_setprio(1);
    #pragma unroll
    for (int m = 0; m < 4; m++)
      #pragma unroll
      for (int n = 0; n < 2; n++)
        #pragma unroll
        for (int ks = 0; ks < 2; ks++)
          ag[4 + m][n] = __builtin_amdgcn_mfma_f32_16x16x32_bf16(a[m][ks], bgv[n][ks], ag[4 + m][n], 0, 0, 0);
    __builtin_amdgcn_s_setprio(0);
    SBARF();
    // ---- ph4: stage hA1(t+1); vmcnt(4); bar; MFMA u/m-hi; bar
    if (more) { GLD16(gA1, sbp + 8192 + sdst); gA1 += BK;
                GLD16(gA3, sbp + 24576 + sdst); gA3 += BK;
                WAITV(4); }
    SBARF();
    __builtin_amdgcn_s_setprio(1);
    #pragma unroll
    for (int m = 0; m < 4; m++)
      #pragma unroll
      for (int n = 0; n < 2; n++)
        #pragma unroll
        for (int ks = 0; ks < 2; ks++)
          au[4 + m][n] = __builtin_amdgcn_mfma_f32_16x16x32_bf16(a[m][ks], buv[n][ks], au[4 + m][n], 0, 0, 0);
    __builtin_amdgcn_s_setprio(0);
    SBARF();
  }

  // epilogue: silu(g)*u, masked bf16 store
  #pragma unroll
  for (int m = 0; m < 8; m++) {
    const int r0 = wr * 128 + (m >> 2) * 64 + (m & 3) * 16 + ((lane >> 4) << 2);
    #pragma unroll
    for (int n = 0; n < 2; n++) {
      const int col = n0 + wc * 32 + n * 16 + (lane & 15);
      #pragma unroll
      for (int j = 0; j < 4; j++) {
        const int r = r0 + j;
        if (r < d.nrows) {
          float gf = ag[m][n][j], uf = au[m][n][j];
          float hv = gf / (1.f + expf(-gf)) * uf;
          h[(size_t)(d.row_start + r) * F_DIM + col] = f2bf(hv);
        }
      }
    }
  }
}

// -------- GEMM2 (R7-proven): eout/out = H @ Wd, 128x256 tile, 2-phase --------
__global__ __launch_bounds__(256, 2) void k_gemm2(
    const u16* __restrict__ h, const u16* __restrict__ WdT, const u16* __restrict__ WdTs,
    const Desc* __restrict__ descs, float* __restrict__ eout, float* __restrict__ out) {
  __shared__ u16 As[BM * BK];
  __shared__ u16 Bs[256 * BK];
  const Desc d = descs[blockIdx.y];
  if (d.nrows <= 0) return;
  const int n0 = (int)blockIdx.x * 256;
  const u16* BT = (d.e == NEXP) ? WdTs : (WdT + (size_t)d.e * D_DIM * F_DIM);
  const int tid = threadIdx.x;
  const int w = tid >> 6, lane = tid & 63;

  const u16* pA[4]; const u16* pB[8]; unsigned aoff[4], boff[8];
  const int lrow = lane >> 3;
  const int col = (((lane & 7) ^ (lrow & 7)) * 8);
  #pragma unroll
  for (int j = 0; j < 4; j++) {
    const int chunk = w * 4 + j;
    pA[j] = h + (size_t)(d.row_start + chunk * 8 + lrow) * F_DIM + col;
    aoff[j] = (unsigned)chunk * 1024u;
  }
  #pragma unroll
  for (int j = 0; j < 8; j++) {
    const int chunk = w * 8 + j;
    pB[j] = BT + (size_t)(n0 + chunk * 8 + lrow) * F_DIM + col;
    boff[j] = (unsigned)chunk * 1024u;
  }

  f32x4 acc[4][8];
  #pragma unroll
  for (int m = 0; m < 4; m++)
    #pragma unroll
    for (int n = 0; n < 8; n++) acc[m][n] = (f32x4)0.f;

  const int wr = w >> 1, wc = w & 1;
  const int sw = lane & 7;
  const u16* aP = As + (wr * 64 + (lane & 15)) * BK;
  const u16* bP = Bs + (wc * 128 + (lane & 15)) * BK;
  const int slot0 = ((lane >> 4) ^ sw) * 8;
  const int slot1 = (((lane >> 4) + 4) ^ sw) * 8;

  for (int k0 = 0; k0 < F_DIM; k0 += BK) {
    #pragma unroll
    for (int j = 0; j < 4; j++) GLD16(pA[j] + k0, (char*)As + aoff[j]);
    #pragma unroll
    for (int j = 0; j < 8; j++) GLD16(pB[j] + k0, (char*)Bs + boff[j]);
    __syncthreads();
    #pragma unroll
    for (int ks = 0; ks < 2; ks++) {
      const int sl = ks ? slot1 : slot0;
      bf16x8 af[4], bf[8];
      #pragma unroll
      for (int m = 0; m < 4; m++) af[m] = *(const bf16x8*)(aP + m * 16 * BK + sl);
      #pragma unroll
      for (int n = 0; n < 8; n++) bf[n] = *(const bf16x8*)(bP + n * 16 * BK + sl);
      #pragma unroll
      for (int m = 0; m < 4; m++)
        #pragma unroll
        for (int n = 0; n < 8; n++)
          acc[m][n] = __builtin_amdgcn_mfma_f32_16x16x32_bf16(af[m], bf[n], acc[m][n], 0, 0, 0);
    }
    __syncthreads();
  }

  #pragma unroll
  for (int m = 0; m < 4; m++) {
    const int rbase = wr * 64 + m * 16 + ((lane >> 4) << 2);
    #pragma unroll
    for (int n = 0; n < 8; n++) {
      const int col2 = n0 + wc * 128 + n * 16 + (lane & 15);
      #pragma unroll
      for (int j = 0; j < 4; j++) {
        const int r = rbase + j;
        if (r < d.nrows) {
          const int grow = d.row_start + r;
          float v = acc[m][n][j];
          if (d.e == NEXP) out[(size_t)(grow - 2 * T_TOK) * D_DIM + col2] = v;
          else             eout[(size_t)grow * D_DIM + col2] = v;
        }
      }
    }
  }
}

// ---------------- combine ----------------
__global__ void k_combine(const float* __restrict__ eout, const int* __restrict__ pos,
                          const float* __restrict__ tk_w, float* __restrict__ out) {
  const int t = blockIdx.x;
  const int dc = threadIdx.x * 4;
  const int p0 = pos[t * 2], p1 = pos[t * 2 + 1];
  const float w0 = tk_w[t * 2], w1 = tk_w[t * 2 + 1];
  float* op = out + (size_t)t * D_DIM + dc;
  float4 o = *(float4*)op;
  float4 a = *(const float4*)(eout + (size_t)p0 * D_DIM + dc);
  float4 b = *(const float4*)(eout + (size_t)p1 * D_DIM + dc);
  o.x += w0 * a.x + w1 * b.x;
  o.y += w0 * a.y + w1 * b.y;
  o.z += w0 * a.z + w1 * b.z;
  o.w += w0 * a.w + w1 * b.w;
  *(float4*)op = o;
}

extern "C" void kernel_launch(void* const* d_in, const int* in_sizes, int n_in,
                              void* d_out, int out_size, void* d_ws, size_t ws_size,
                              hipStream_t stream) {
  const float* X    = (const float*)d_in[0];
  const float* Wr   = (const float*)d_in[1];
  const float* Wg_s = (const float*)d_in[2];
  const float* Wu_s = (const float*)d_in[3];
  const float* Wd_s = (const float*)d_in[4];
  const float* Wg   = (const float*)d_in[5];
  const float* Wu   = (const float*)d_in[6];
  const float* Wd   = (const float*)d_in[7];
  float* out = (float*)d_out;

  char* ws = (char*)d_ws;
  size_t o = 0;
  auto alloc = [&](size_t bytes) -> void* {
    void* p = ws + o;
    o += (bytes + 255) & ~(size_t)255;
    return p;
  };
  u16* Xb    = (u16*)alloc((size_t)T_TOK * D_DIM * 2);
  u16* WgTs  = (u16*)alloc((size_t)F_DIM * D_DIM * 2);
  u16* WuTs  = (u16*)alloc((size_t)F_DIM * D_DIM * 2);
  u16* WdTs  = (u16*)alloc((size_t)D_DIM * F_DIM * 2);
  u16* WgT   = (u16*)alloc((size_t)NEXP * F_DIM * D_DIM * 2);
  u16* WuT   = (u16*)alloc((size_t)NEXP * F_DIM * D_DIM * 2);
  u16* WdT   = (u16*)alloc((size_t)NEXP * D_DIM * F_DIM * 2);
  u16* h     = (u16*)alloc((size_t)(3 * T_TOK) * F_DIM * 2);
  float* eout= (float*)alloc((size_t)(2 * T_TOK) * D_DIM * 4);
  int* tk_idx= (int*)alloc((size_t)T_TOK * 2 * 4);
  float* tk_w= (float*)alloc((size_t)T_TOK * 2 * 4);
  int* pos   = (int*)alloc((size_t)T_TOK * 2 * 4);
  int* tok   = (int*)alloc((size_t)(3 * T_TOK) * 4);
  int* meta  = (int*)alloc(256);
  Desc* descs1 = (Desc*)alloc(NDESC1 * sizeof(Desc));
  Desc* descs2 = (Desc*)alloc(NDESC2 * sizeof(Desc));
  if (o > ws_size) return;

  int* counts = meta, *offsets = meta + 8, *cursors = meta + 16;

  k_tconv_all<<<dim3(16, 32, 27), 256, 0, stream>>>(Wg_s, Wu_s, Wd_s, Wg, Wu, Wd,
                                                    WgTs, WuTs, WdTs, WgT, WuT, WdT, meta);
  k_router<<<T_TOK / 4, 256, 0, stream>>>(X, Wr, Xb, tk_idx, tk_w, counts);
  k_scan<<<1, 64, 0, stream>>>(counts, offsets, cursors, descs1, descs2);
  k_scatter<<<T_TOK / 256, 256, 0, stream>>>(tk_idx, offsets, cursors, tok, pos);
  k_gemm1<<<dim3(16, NDESC1), 512, 0, stream>>>(Xb, WgT, WuT, WgTs, WuTs, tok, descs1, h);
  k_gemm2<<<dim3(4, NDESC2), 256, 0, stream>>>(h, WdT, WdTs, descs2, eout, out);
  k_combine<<<T_TOK, 256, 0, stream>>>(eout, pos, tk_w, out);
}

// Round 9
// 407.542 us; speedup vs baseline: 1.0195x; 1.0195x over previous
//
#include <hip/hip_runtime.h>
#include <stdint.h>

typedef unsigned short u16;
typedef __attribute__((ext_vector_type(8))) short bf16x8;
typedef __attribute__((ext_vector_type(4))) float f32x4;

#define T_TOK 4096
#define D_DIM 1024
#define F_DIM 2048
#define NEXP 8
#define BM 128
#define BK 64
#define NDESC 112

struct Desc { int row_start; int nrows; int e; int pad; };

__device__ __forceinline__ u16 f2bf(float x) {
  union { float f; unsigned u; } v; v.f = x;
  unsigned r = v.u + 0x7FFFu + ((v.u >> 16) & 1u);
  return (u16)(r >> 16);
}

#define GLD16(g, l) __builtin_amdgcn_global_load_lds( \
    (const __attribute__((address_space(1))) unsigned int*)(const void*)(g), \
    (__attribute__((address_space(3))) unsigned int*)(void*)(l), 16, 0, 0)

// ------ convert + transpose ALL weights; grid (16,32,27); zeroes meta once ------
__global__ void k_tconv_all(const float* __restrict__ Wg_s, const float* __restrict__ Wu_s,
                            const float* __restrict__ Wd_s, const float* __restrict__ Wg,
                            const float* __restrict__ Wu, const float* __restrict__ Wd,
                            u16* __restrict__ WgTs, u16* __restrict__ WuTs,
                            u16* __restrict__ WdTs, u16* __restrict__ WgT,
                            u16* __restrict__ WuT, u16* __restrict__ WdT,
                            int* __restrict__ meta) {
  if (blockIdx.x == 0 && blockIdx.y == 0 && blockIdx.z == 0 && threadIdx.x < 32)
    meta[threadIdx.x] = 0;
  const int z = blockIdx.z;
  const float* src; u16* dst; int R, C;
  const size_t sz = (size_t)D_DIM * F_DIM;
  if (z < 8)       { src = Wg + sz * z;        dst = WgT + sz * z;        R = D_DIM; C = F_DIM; }
  else if (z < 16) { src = Wu + sz * (z - 8);  dst = WuT + sz * (z - 8);  R = D_DIM; C = F_DIM; }
  else if (z < 24) { src = Wd + sz * (z - 16); dst = WdT + sz * (z - 16); R = F_DIM; C = D_DIM; }
  else if (z == 24){ src = Wg_s; dst = WgTs; R = D_DIM; C = F_DIM; }
  else if (z == 25){ src = Wu_s; dst = WuTs; R = D_DIM; C = F_DIM; }
  else             { src = Wd_s; dst = WdTs; R = F_DIM; C = D_DIM; }
  const bool tall = (R > C);
  const int rb = (tall ? blockIdx.y : blockIdx.x) * 64;
  const int cb = (tall ? blockIdx.x : blockIdx.y) * 64;
  __shared__ u16 tile[64][72];
  const int tid = threadIdx.x;
  const int lr = tid >> 4, lc = (tid & 15) * 4;
  #pragma unroll
  for (int p = 0; p < 4; p++) {
    int r = p * 16 + lr;
    float4 v = *(const float4*)(src + (size_t)(rb + r) * C + cb + lc);
    tile[r][lc + 0] = f2bf(v.x); tile[r][lc + 1] = f2bf(v.y);
    tile[r][lc + 2] = f2bf(v.z); tile[r][lc + 3] = f2bf(v.w);
  }
  __syncthreads();
  #pragma unroll
  for (int it = 0; it < 2; it++) {
    int chunk = it * 256 + tid;
    int c = chunk >> 3, r0 = (chunk & 7) * 8;
    u16 o[8];
    #pragma unroll
    for (int i = 0; i < 8; i++) o[i] = tile[r0 + i][c];
    *(uint4*)(dst + (size_t)(cb + c) * R + rb + r0) = *(const uint4*)o;
  }
}

// ------- router (fp32 logits, softmax, top-2, re-softmax) + X->bf16 convert -------
__global__ void k_router(const float* __restrict__ X, const float* __restrict__ Wr,
                         u16* __restrict__ Xb, int* __restrict__ tk_idx,
                         float* __restrict__ tk_w, int* __restrict__ counts) {
  const int w = threadIdx.x >> 6, lane = threadIdx.x & 63;
  const int t = blockIdx.x * 4 + w;
  float acc[8] = {0.f, 0.f, 0.f, 0.f, 0.f, 0.f, 0.f, 0.f};
  const float* xr = X + (size_t)t * D_DIM;
  u16* xb = Xb + (size_t)t * D_DIM;
  #pragma unroll
  for (int it = 0; it < 4; it++) {
    const int i0 = it * 256 + lane * 4;
    float4 xv = *(const float4*)(xr + i0);
    union { u16 a[4]; uint2 v; } ob;
    ob.a[0] = f2bf(xv.x); ob.a[1] = f2bf(xv.y); ob.a[2] = f2bf(xv.z); ob.a[3] = f2bf(xv.w);
    *(uint2*)(xb + i0) = ob.v;
    float xs[4] = {xv.x, xv.y, xv.z, xv.w};
    #pragma unroll
    for (int j = 0; j < 4; j++) {
      const float4* wrp = (const float4*)(Wr + (size_t)(i0 + j) * 8);
      float4 w0 = wrp[0], w1 = wrp[1];
      float x = xs[j];
      acc[0] += x * w0.x; acc[1] += x * w0.y; acc[2] += x * w0.z; acc[3] += x * w0.w;
      acc[4] += x * w1.x; acc[5] += x * w1.y; acc[6] += x * w1.z; acc[7] += x * w1.w;
    }
  }
  #pragma unroll
  for (int m = 32; m; m >>= 1) {
    #pragma unroll
    for (int e = 0; e < 8; e++) acc[e] += __shfl_xor(acc[e], m);
  }
  float mx = acc[0];
  #pragma unroll
  for (int e = 1; e < 8; e++) mx = fmaxf(mx, acc[e]);
  float p[8], Z = 0.f;
  #pragma unroll
  for (int e = 0; e < 8; e++) { p[e] = expf(acc[e] - mx); Z += p[e]; }
  float inv = 1.f / Z;
  #pragma unroll
  for (int e = 0; e < 8; e++) p[e] *= inv;
  int e1 = 0; float p1 = p[0];
  #pragma unroll
  for (int e = 1; e < 8; e++) if (p[e] > p1) { p1 = p[e]; e1 = e; }
  int e2 = -1; float p2 = -1.f;
  #pragma unroll
  for (int e = 0; e < 8; e++) if (e != e1 && p[e] > p2) { p2 = p[e]; e2 = e; }
  float bb = expf(p2 - p1);
  float w1v = 1.f / (1.f + bb), w2v = 1.f - w1v;
  if (lane == 0) {
    tk_idx[t * 2] = e1; tk_idx[t * 2 + 1] = e2;
    tk_w[t * 2] = w1v;  tk_w[t * 2 + 1] = w2v;
    atomicAdd(&counts[e1], 1); atomicAdd(&counts[e2], 1);
  }
}

// ------------- scan + 128-row tile descriptors (parallel) -------------
__global__ void k_scan(const int* __restrict__ counts, int* __restrict__ offsets,
                       int* __restrict__ cursors, Desc* __restrict__ descs) {
  const int lane = threadIdx.x;
  int cnt[8], off[9], tst[9];
  off[0] = 0; tst[0] = 0;
  #pragma unroll
  for (int e = 0; e < 8; e++) {
    cnt[e] = counts[e];
    off[e + 1] = off[e] + cnt[e];
    tst[e + 1] = tst[e] + ((cnt[e] + 127) >> 7);
  }
  if (lane < 8) { offsets[lane] = off[lane]; cursors[lane] = 0; }
  const int tr = tst[8];
  for (int i = lane; i < NDESC; i += 64) {
    Desc dd; dd.nrows = 0; dd.row_start = 0; dd.e = 0; dd.pad = 0;
    if (i < tr) {
      int e = 0;
      #pragma unroll
      for (int q = 0; q < 7; q++) if (i >= tst[q + 1]) e = q + 1;
      int s = (i - tst[e]) << 7;
      dd.row_start = off[e] + s;
      int rem = cnt[e] - s;
      dd.nrows = rem < 128 ? rem : 128;
      dd.e = e;
    } else if (i < tr + T_TOK / 128) {
      int j = i - tr;
      dd.row_start = 2 * T_TOK + j * 128; dd.nrows = 128; dd.e = NEXP;
    }
    descs[i] = dd;
  }
}

// ---------------- scatter ----------------
__global__ void k_scatter(const int* __restrict__ tk_idx, const int* __restrict__ offsets,
                          int* __restrict__ cursors, int* __restrict__ tok,
                          int* __restrict__ pos) {
  int t = blockIdx.x * 256 + threadIdx.x;
  if (t >= T_TOK) return;
  #pragma unroll
  for (int k = 0; k < 2; k++) {
    int e = tk_idx[t * 2 + k];
    int pp = atomicAdd(&cursors[e], 1);
    int a = offsets[e] + pp;
    tok[a] = t;
    pos[t * 2 + k] = a;
  }
  tok[2 * T_TOK + t] = t;
}

// ======== GEMM1 fused, low-register: h = silu(X@Wg^T) * (X@Wu^T) ========
// BM=128, BN=64(g)+64(u), BK=64; grid (32, NDESC) = 3584 blocks, 256 thr.
// 4 waves 2M x 2N; per-wave 64 rows x (32 g-cols + 32 u-cols):
// acc = ag[4][2]+au[4][2] = 16 f32x4 = 64 AGPR (vs 128 in R3) -> with ~80 arch
// VGPR, unified total ~150 -> 3 waves/SIMD (was 2). LDS 32KB (As16|Bg8|Bu8).
// Same proven 2-phase loop + T2 XOR swizzle (inverse-swizzled source, linear
// gld_lds dest, swizzled ds_read). Silu stays fused in-wave.
__global__ __launch_bounds__(256, 3) void k_gemm1(
    const u16* __restrict__ Xb, const u16* __restrict__ WgT, const u16* __restrict__ WuT,
    const u16* __restrict__ WgTs, const u16* __restrict__ WuTs,
    const int* __restrict__ tok, const Desc* __restrict__ descs, u16* __restrict__ h) {
  __shared__ u16 As[128 * BK];        // 16 KB
  __shared__ u16 Bgs[64 * BK];        // 8 KB
  __shared__ u16 Bus[64 * BK];        // 8 KB
  const Desc d = descs[blockIdx.y];
  if (d.nrows <= 0) return;
  const int n0 = (int)blockIdx.x * 64;
  const u16* BTg = (d.e == NEXP) ? WgTs : (WgT + (size_t)d.e * F_DIM * D_DIM);
  const u16* BTu = (d.e == NEXP) ? WuTs : (WuT + (size_t)d.e * F_DIM * D_DIM);
  const int tid = threadIdx.x;
  const int w = tid >> 6, lane = tid & 63;

  // staging sources: each GLD16 sweep = 256thr*16B = 4KB = 32 rows
  const int srow = tid >> 3;                        // 0..31 within chunk
  const int scol = ((tid & 7) ^ (srow & 7)) * 8;    // inverse-swizzled source col
  const u16* pA[4]; const u16* pBg[2]; const u16* pBu[2];
  #pragma unroll
  for (int j = 0; j < 4; j++)
    pA[j] = Xb + (size_t)tok[d.row_start + j * 32 + srow] * D_DIM + scol;
  #pragma unroll
  for (int j = 0; j < 2; j++) {
    pBg[j] = BTg + (size_t)(n0 + j * 32 + srow) * D_DIM + scol;
    pBu[j] = BTu + (size_t)(n0 + j * 32 + srow) * D_DIM + scol;
  }
  const unsigned sdst = (unsigned)tid * 16;

  f32x4 ag[4][2], au[4][2];
  #pragma unroll
  for (int m = 0; m < 4; m++)
    #pragma unroll
    for (int n = 0; n < 2; n++) { ag[m][n] = (f32x4)0.f; au[m][n] = (f32x4)0.f; }

  const int wr = w >> 1, wc = w & 1;
  const int sw = lane & 7;
  const u16* aP = As  + (wr * 64 + (lane & 15)) * BK;
  const u16* gP = Bgs + (wc * 32 + (lane & 15)) * BK;
  const u16* uP = Bus + (wc * 32 + (lane & 15)) * BK;
  const int slot0 = ((lane >> 4) ^ sw) * 8;
  const int slot1 = (((lane >> 4) + 4) ^ sw) * 8;

  for (int k0 = 0; k0 < D_DIM; k0 += BK) {
    #pragma unroll
    for (int j = 0; j < 4; j++) GLD16(pA[j] + k0,  (char*)As  + j * 4096 + sdst);
    #pragma unroll
    for (int j = 0; j < 2; j++) GLD16(pBg[j] + k0, (char*)Bgs + j * 4096 + sdst);
    #pragma unroll
    for (int j = 0; j < 2; j++) GLD16(pBu[j] + k0, (char*)Bus + j * 4096 + sdst);
    __syncthreads();
    #pragma unroll
    for (int ks = 0; ks < 2; ks++) {
      const int sl = ks ? slot1 : slot0;
      bf16x8 af[4], bg[2], bu[2];
      #pragma unroll
      for (int m = 0; m < 4; m++) af[m] = *(const bf16x8*)(aP + m * 16 * BK + sl);
      #pragma unroll
      for (int n = 0; n < 2; n++) { bg[n] = *(const bf16x8*)(gP + n * 16 * BK + sl);
                                    bu[n] = *(const bf16x8*)(uP + n * 16 * BK + sl); }
      #pragma unroll
      for (int m = 0; m < 4; m++)
        #pragma unroll
        for (int n = 0; n < 2; n++) {
          ag[m][n] = __builtin_amdgcn_mfma_f32_16x16x32_bf16(af[m], bg[n], ag[m][n], 0, 0, 0);
          au[m][n] = __builtin_amdgcn_mfma_f32_16x16x32_bf16(af[m], bu[n], au[m][n], 0, 0, 0);
        }
    }
    __syncthreads();
  }

  // epilogue: silu(g)*u, masked bf16 store
  #pragma unroll
  for (int m = 0; m < 4; m++) {
    const int rbase = wr * 64 + m * 16 + ((lane >> 4) << 2);
    #pragma unroll
    for (int n = 0; n < 2; n++) {
      const int col = n0 + wc * 32 + n * 16 + (lane & 15);
      #pragma unroll
      for (int j = 0; j < 4; j++) {
        const int r = rbase + j;
        if (r < d.nrows) {
          float gf = ag[m][n][j], uf = au[m][n][j];
          float hv = gf / (1.f + expf(-gf)) * uf;
          h[(size_t)(d.row_start + r) * F_DIM + col] = f2bf(hv);
        }
      }
    }
  }
}

// -------- GEMM2 (R7-proven, untouched): eout/out = H @ Wd, 128x256, 2-phase --------
__global__ __launch_bounds__(256, 2) void k_gemm2(
    const u16* __restrict__ h, const u16* __restrict__ WdT, const u16* __restrict__ WdTs,
    const Desc* __restrict__ descs, float* __restrict__ eout, float* __restrict__ out) {
  __shared__ u16 As[BM * BK];
  __shared__ u16 Bs[256 * BK];
  const Desc d = descs[blockIdx.y];
  if (d.nrows <= 0) return;
  const int n0 = (int)blockIdx.x * 256;
  const u16* BT = (d.e == NEXP) ? WdTs : (WdT + (size_t)d.e * D_DIM * F_DIM);
  const int tid = threadIdx.x;
  const int w = tid >> 6, lane = tid & 63;

  const u16* pA[4]; const u16* pB[8]; unsigned aoff[4], boff[8];
  const int lrow = lane >> 3;
  const int col = (((lane & 7) ^ (lrow & 7)) * 8);
  #pragma unroll
  for (int j = 0; j < 4; j++) {
    const int chunk = w * 4 + j;
    pA[j] = h + (size_t)(d.row_start + chunk * 8 + lrow) * F_DIM + col;
    aoff[j] = (unsigned)chunk * 1024u;
  }
  #pragma unroll
  for (int j = 0; j < 8; j++) {
    const int chunk = w * 8 + j;
    pB[j] = BT + (size_t)(n0 + chunk * 8 + lrow) * F_DIM + col;
    boff[j] = (unsigned)chunk * 1024u;
  }

  f32x4 acc[4][8];
  #pragma unroll
  for (int m = 0; m < 4; m++)
    #pragma unroll
    for (int n = 0; n < 8; n++) acc[m][n] = (f32x4)0.f;

  const int wr = w >> 1, wc = w & 1;
  const int sw = lane & 7;
  const u16* aP = As + (wr * 64 + (lane & 15)) * BK;
  const u16* bP = Bs + (wc * 128 + (lane & 15)) * BK;
  const int slot0 = ((lane >> 4) ^ sw) * 8;
  const int slot1 = (((lane >> 4) + 4) ^ sw) * 8;

  for (int k0 = 0; k0 < F_DIM; k0 += BK) {
    #pragma unroll
    for (int j = 0; j < 4; j++) GLD16(pA[j] + k0, (char*)As + aoff[j]);
    #pragma unroll
    for (int j = 0; j < 8; j++) GLD16(pB[j] + k0, (char*)Bs + boff[j]);
    __syncthreads();
    #pragma unroll
    for (int ks = 0; ks < 2; ks++) {
      const int sl = ks ? slot1 : slot0;
      bf16x8 af[4], bf[8];
      #pragma unroll
      for (int m = 0; m < 4; m++) af[m] = *(const bf16x8*)(aP + m * 16 * BK + sl);
      #pragma unroll
      for (int n = 0; n < 8; n++) bf[n] = *(const bf16x8*)(bP + n * 16 * BK + sl);
      #pragma unroll
      for (int m = 0; m < 4; m++)
        #pragma unroll
        for (int n = 0; n < 8; n++)
          acc[m][n] = __builtin_amdgcn_mfma_f32_16x16x32_bf16(af[m], bf[n], acc[m][n], 0, 0, 0);
    }
    __syncthreads();
  }

  #pragma unroll
  for (int m = 0; m < 4; m++) {
    const int rbase = wr * 64 + m * 16 + ((lane >> 4) << 2);
    #pragma unroll
    for (int n = 0; n < 8; n++) {
      const int col2 = n0 + wc * 128 + n * 16 + (lane & 15);
      #pragma unroll
      for (int j = 0; j < 4; j++) {
        const int r = rbase + j;
        if (r < d.nrows) {
          const int grow = d.row_start + r;
          float v = acc[m][n][j];
          if (d.e == NEXP) out[(size_t)(grow - 2 * T_TOK) * D_DIM + col2] = v;
          else             eout[(size_t)grow * D_DIM + col2] = v;
        }
      }
    }
  }
}

// ---------------- combine ----------------
__global__ void k_combine(const float* __restrict__ eout, const int* __restrict__ pos,
                          const float* __restrict__ tk_w, float* __restrict__ out) {
  const int t = blockIdx.x;
  const int dc = threadIdx.x * 4;
  const int p0 = pos[t * 2], p1 = pos[t * 2 + 1];
  const float w0 = tk_w[t * 2], w1 = tk_w[t * 2 + 1];
  float* op = out + (size_t)t * D_DIM + dc;
  float4 o = *(float4*)op;
  float4 a = *(const float4*)(eout + (size_t)p0 * D_DIM + dc);
  float4 b = *(const float4*)(eout + (size_t)p1 * D_DIM + dc);
  o.x += w0 * a.x + w1 * b.x;
  o.y += w0 * a.y + w1 * b.y;
  o.z += w0 * a.z + w1 * b.z;
  o.w += w0 * a.w + w1 * b.w;
  *(float4*)op = o;
}

extern "C" void kernel_launch(void* const* d_in, const int* in_sizes, int n_in,
                              void* d_out, int out_size, void* d_ws, size_t ws_size,
                              hipStream_t stream) {
  const float* X    = (const float*)d_in[0];
  const float* Wr   = (const float*)d_in[1];
  const float* Wg_s = (const float*)d_in[2];
  const float* Wu_s = (const float*)d_in[3];
  const float* Wd_s = (const float*)d_in[4];
  const float* Wg   = (const float*)d_in[5];
  const float* Wu   = (const float*)d_in[6];
  const float* Wd   = (const float*)d_in[7];
  float* out = (float*)d_out;

  char* ws = (char*)d_ws;
  size_t o = 0;
  auto alloc = [&](size_t bytes) -> void* {
    void* p = ws + o;
    o += (bytes + 255) & ~(size_t)255;
    return p;
  };
  u16* Xb    = (u16*)alloc((size_t)T_TOK * D_DIM * 2);
  u16* WgTs  = (u16*)alloc((size_t)F_DIM * D_DIM * 2);
  u16* WuTs  = (u16*)alloc((size_t)F_DIM * D_DIM * 2);
  u16* WdTs  = (u16*)alloc((size_t)D_DIM * F_DIM * 2);
  u16* WgT   = (u16*)alloc((size_t)NEXP * F_DIM * D_DIM * 2);
  u16* WuT   = (u16*)alloc((size_t)NEXP * F_DIM * D_DIM * 2);
  u16* WdT   = (u16*)alloc((size_t)NEXP * D_DIM * F_DIM * 2);
  u16* h     = (u16*)alloc((size_t)(3 * T_TOK) * F_DIM * 2);
  float* eout= (float*)alloc((size_t)(2 * T_TOK) * D_DIM * 4);
  int* tk_idx= (int*)alloc((size_t)T_TOK * 2 * 4);
  float* tk_w= (float*)alloc((size_t)T_TOK * 2 * 4);
  int* pos   = (int*)alloc((size_t)T_TOK * 2 * 4);
  int* tok   = (int*)alloc((size_t)(3 * T_TOK) * 4);
  int* meta  = (int*)alloc(256);
  Desc* descs= (Desc*)alloc(NDESC * sizeof(Desc));
  if (o > ws_size) return;

  int* counts = meta, *offsets = meta + 8, *cursors = meta + 16;

  k_tconv_all<<<dim3(16, 32, 27), 256, 0, stream>>>(Wg_s, Wu_s, Wd_s, Wg, Wu, Wd,
                                                    WgTs, WuTs, WdTs, WgT, WuT, WdT, meta);
  k_router<<<T_TOK / 4, 256, 0, stream>>>(X, Wr, Xb, tk_idx, tk_w, counts);
  k_scan<<<1, 64, 0, stream>>>(counts, offsets, cursors, descs);
  k_scatter<<<T_TOK / 256, 256, 0, stream>>>(tk_idx, offsets, cursors, tok, pos);
  k_gemm1<<<dim3(32, NDESC), 256, 0, stream>>>(Xb, WgT, WuT, WgTs, WuTs, tok, descs, h);
  k_gemm2<<<dim3(4, NDESC), 256, 0, stream>>>(h, WdT, WdTs, descs, eout, out);
  k_combine<<<T_TOK, 256, 0, stream>>>(eout, pos, tk_w, out);
}